// Round 5
// baseline (205.236 us; speedup 1.0000x reference)
//
#include <hip/hip_runtime.h>
#include <math.h>
#include <stdint.h>

#define VOCAB 100000
#define NB    1024
#define QLEN  32
#define DLEN  256
#define EMBED 128
#define KNUM  11

typedef __attribute__((ext_vector_type(8))) short bf16x8;   // 8 bf16 = 4 VGPRs
typedef __attribute__((ext_vector_type(4))) float f32x4;

// Gaussian chain: mus -0.9..0.9 step 0.2 (sigma 0.1) + exact mu=1 sigma=.001
#define HALF_L2E 0.7213475204444817f   // 0.5*log2(e)
#define TWO_L2E  2.8853900817779268f   // 2*log2(e)
#define EM4      0.018315638888734179f // e^-4

#define SSTR  68                 // row stride (floats): 16B-aligned, 2-way bank alias = free
#define SHALF (16 * SSTR)        // legacy fallback half-tile
#define WROWS 32                 // pipelined kernel: 32 sim rows per wave
#define WTILE_F (WROWS * SSTR)

// ---------- prepass: fp32 table -> bf16 table + bf16-consistent inv-norms ----
__global__ __launch_bounds__(256)
void cvt_table(const float* __restrict__ emb, ushort* __restrict__ ebf,
               float* __restrict__ inorm)
{
    const int row = blockIdx.x * 8 + (threadIdx.x >> 5);
    const int l32 = threadIdx.x & 31;
    const float4 v = *((const float4*)(emb + (size_t)row * EMBED) + l32);
    union { float f; unsigned u; } x0, x1, x2, x3;
    x0.f = v.x; x1.f = v.y; x2.f = v.z; x3.f = v.w;
    const unsigned r0 = x0.u + 0x8000u, r1 = x1.u + 0x8000u;  // round-half-up
    const unsigned r2 = x2.u + 0x8000u, r3 = x3.u + 0x8000u;
    uint2 packed;
    packed.x = (r0 >> 16) | (r1 & 0xFFFF0000u);
    packed.y = (r2 >> 16) | (r3 & 0xFFFF0000u);
    *((uint2*)(ebf + (size_t)row * EMBED) + l32) = packed;
    x0.u = r0 & 0xFFFF0000u; x1.u = r1 & 0xFFFF0000u;
    x2.u = r2 & 0xFFFF0000u; x3.u = r3 & 0xFFFF0000u;
    float n = x0.f * x0.f + x1.f * x1.f + x2.f * x2.f + x3.f * x3.f;
    #pragma unroll
    for (int m = 1; m < 32; m <<= 1) n += __shfl_xor(n, m);
    if (l32 == 0) inorm[row] = __builtin_amdgcn_rsqf(n);
}

// ---------------------------------------------------------------------------
// helpers for the pipelined kernel
__device__ __forceinline__ void load_ids(const int* __restrict__ qp,
                                         const int* __restrict__ dp,
                                         int w, int l15,
                                         int& q0, int& q1, int (&dd)[4])
{
    q0 = qp[l15];
    q1 = qp[l15 + 16];
    #pragma unroll
    for (int j = 0; j < 4; ++j) dd[j] = dp[(w * 4 + j) * 16 + l15];
}

__device__ __forceinline__ void issue_frags(const ushort* __restrict__ ebf,
                                            const float* __restrict__ inorm,
                                            const int* __restrict__ qp,
                                            int quad,
                                            int q0, int q1, const int (&dd)[4],
                                            bf16x8 (&a0)[4], bf16x8 (&a1)[4],
                                            bf16x8 (&bbf)[4][4],
                                            float (&idn)[4], float (&riq)[2][4])
{
    const ushort* qp0 = ebf + (size_t)q0 * EMBED + quad * 8;
    const ushort* qp1 = ebf + (size_t)q1 * EMBED + quad * 8;
    #pragma unroll
    for (int kk = 0; kk < 4; ++kk) {
        a0[kk] = *(const bf16x8*)(qp0 + kk * 32);
        a1[kk] = *(const bf16x8*)(qp1 + kk * 32);
    }
    #pragma unroll
    for (int j = 0; j < 4; ++j) {
        const ushort* dp = ebf + (size_t)dd[j] * EMBED + quad * 8;
        #pragma unroll
        for (int kk = 0; kk < 4; ++kk)
            bbf[j][kk] = *(const bf16x8*)(dp + kk * 32);
    }
    #pragma unroll
    for (int j = 0; j < 4; ++j) idn[j] = inorm[dd[j]];
    #pragma unroll
    for (int r = 0; r < 4; ++r) {
        riq[0][r] = inorm[qp[quad * 4 + r]];
        riq[1][r] = inorm[qp[16 + quad * 4 + r]];
    }
}

// the 11-kernel exp chain on one f32x4 of sims (byte-identical to legacy)
__device__ __forceinline__ void chain4(const f32x4 sv, float (&ksum)[KNUM])
{
    #pragma unroll
    for (int e = 0; e < 4; ++e) {
        const float s  = sv[e];
        const float z  = fmaf(s, 10.f, -1.f);
        const float e0 = exp2f(-HALF_L2E * (z * z));
        float ru = exp2f(fmaf(z,  TWO_L2E, -TWO_L2E));
        float rd = exp2f(fmaf(z, -TWO_L2E, -TWO_L2E));
        ksum[5] += e0;
        float tt = e0;
        tt *= ru; ksum[6] += tt; ru *= EM4;
        tt *= ru; ksum[7] += tt; ru *= EM4;
        tt *= ru; ksum[8] += tt; ru *= EM4;
        tt *= ru; ksum[9] += tt;
        tt = e0;
        tt *= rd; ksum[4] += tt; rd *= EM4;
        tt *= rd; ksum[3] += tt; rd *= EM4;
        tt *= rd; ksum[2] += tt; rd *= EM4;
        tt *= rd; ksum[1] += tt; rd *= EM4;
        tt *= rd; ksum[0] += tt;
        // exact kernel (sigma=.001): ==1 iff token match (bf16 self-sim
        // 1+-3e-6; non-match needs cos>0.995 ~ 11 sigma)
        ksum[10] += (s > 0.995f) ? 1.f : 0.f;
    }
}

// ---------------------------------------------------------------------------
// One pipeline stage: MFMA(u) -> sims to LDS -> prefetch(u+1 frags, u+2 ids)
// -> sched_barrier -> pool chain -> final reduce/store for unit u.
// All prefetch state is in caller registers (A/B id sets alternated at the
// CALL SITE with static names - no runtime-indexed arrays, rule #20).
template<int U>
__device__ __forceinline__ void knrm_unit(
    const ushort* __restrict__ ebf, const float* __restrict__ inorm,
    const float* __restrict__ mlp_w, float* __restrict__ logits,
    int unitIdx,
    const int* __restrict__ qpNext,                       // q ids row of unit U+1
    const int* __restrict__ qpNext2, const int* __restrict__ dpNext2,  // unit U+2
    int w, int l15, int quad, int t,
    bf16x8 (&a0)[4], bf16x8 (&a1)[4], bf16x8 (&bbf)[4][4],
    float (&idn)[4], float (&riq)[2][4],
    int& qN0, int& qN1, int (&ddN)[4],      // ids of unit U+1 (consumed here)
    int& qM0, int& qM1, int (&ddM)[4],      // dest for ids of unit U+2
    float* __restrict__ wtile,
    float (*__restrict__ stot)[QLEN][12])
{
    constexpr int PBUF = U & 1;

    // ---- MFMA: frags for unit U (compiler-inserted vmcnt waits here) ----
    f32x4 acc[2][4];
    #pragma unroll
    for (int mt = 0; mt < 2; ++mt)
        #pragma unroll
        for (int j = 0; j < 4; ++j)
            acc[mt][j] = (f32x4){0.f, 0.f, 0.f, 0.f};
    #pragma unroll
    for (int kk = 0; kk < 4; ++kk)
        #pragma unroll
        for (int j = 0; j < 4; ++j) {
            acc[0][j] = __builtin_amdgcn_mfma_f32_16x16x32_bf16(a0[kk], bbf[j][kk], acc[0][j], 0, 0, 0);
            acc[1][j] = __builtin_amdgcn_mfma_f32_16x16x32_bf16(a1[kk], bbf[j][kk], acc[1][j], 0, 0, 0);
        }

    // ---- sims -> wave-private LDS tile (frees acc + this unit's norms) ----
    #pragma unroll
    for (int mt = 0; mt < 2; ++mt)
        #pragma unroll
        for (int j = 0; j < 4; ++j)
            #pragma unroll
            for (int r = 0; r < 4; ++r)
                wtile[(mt * 16 + quad * 4 + r) * SSTR + j * 16 + l15] =
                    acc[mt][j][r] * riq[mt][r] * idn[j];

    // ---- prefetch: frags+norms for U+1 (reg WAR after the reads above),
    //      ids for U+2. Fenced so they cannot sink into the pool phase. ----
    if constexpr (U < 3)
        issue_frags(ebf, inorm, qpNext, quad, qN0, qN1, ddN, a0, a1, bbf, idn, riq);
    if constexpr (U < 2)
        load_ids(qpNext2, dpNext2, w, l15, qM0, qM1, ddM);
    __builtin_amdgcn_sched_barrier(0);

    // ---- pool: read own rows, exp chain, quad-reduce, atomics ----
    #pragma unroll
    for (int mt = 0; mt < 2; ++mt) {
        const float* rp = wtile + (mt * 16 + l15) * SSTR + quad * 16;
        float ksum[KNUM];
        #pragma unroll
        for (int k = 0; k < KNUM; ++k) ksum[k] = 0.f;
        #pragma unroll
        for (int i = 0; i < 4; ++i)
            chain4(*(const f32x4*)(rp + 4 * i), ksum);
        #pragma unroll
        for (int k = 0; k < KNUM; ++k) {
            ksum[k] += __shfl_xor(ksum[k], 16);
            ksum[k] += __shfl_xor(ksum[k], 32);
        }
        if (quad == 0) {
            #pragma unroll
            for (int k = 0; k < KNUM; ++k)
                atomicAdd(&stot[PBUF][mt * 16 + l15][k], ksum[k]);
        }
    }
    __syncthreads();                         // all atomics for unit U done

    // ---- final reduce + store; reader re-zeros its own row for unit U+2 ----
    if (t < QLEN) {
        float c = 0.f;
        #pragma unroll
        for (int k = 0; k < KNUM; ++k) {
            c += mlp_w[k] * log1pf(stot[PBUF][t][k]);
            stot[PBUF][t][k] = 0.f;
        }
        #pragma unroll
        for (int mm = 1; mm < 32; mm <<= 1) c += __shfl_xor(c, mm);
        if (t == 0) logits[unitIdx] = c;     // mlp bias cancels in l1-l2
    }
    // no extra barrier: unit U+1 uses buffer PBUF^1; buffer PBUF is next
    // touched (atomics of U+2) only after the __syncthreads inside unit U+1,
    // which orders it after the zeroing above.
}

// ---------------------------------------------------------------------------
// Round-5: persistent 4-unit blocks, cross-unit software pipeline.
// grid = 512 blocks (2/CU, co-resident, no occupancy decay). Per unit the
// ~3k-cycle pooling phase hides the next unit's 30 gather loads + the
// unit-after-next's id loads.
__global__ __launch_bounds__(256, 3)
void knrm_pair5(const ushort* __restrict__ ebf,
                const float* __restrict__ inorm,
                const float* __restrict__ mlp_w,
                const int* __restrict__ q1, const int* __restrict__ d1,
                const int* __restrict__ q2, const int* __restrict__ d2,
                float* __restrict__ logits)
{
    const int t    = threadIdx.x;
    const int w    = t >> 6;
    const int l15  = t & 15;
    const int quad = (t & 63) >> 4;

    const int unit0 = blockIdx.x * 4;          // 4 | 1024 -> same pair for all 4
    const int pair  = unit0 >> 10;
    const int b0    = unit0 & 1023;
    const int* __restrict__ qb = (pair ? q2 : q1);
    const int* __restrict__ db = (pair ? d2 : d1);

    __shared__ __align__(16) float s_sim[4 * WTILE_F];   // 34816 B
    __shared__ float s_tot[2][QLEN][12];                 // 3072 B
    float* wtile = s_sim + w * WTILE_F;

    // id double-buffer A/B + frag/norm registers (single set, pipelined)
    int qidA0, qidA1, didA[4];
    int qidB0, qidB1, didB[4];
    bf16x8 a0[4], a1[4], bbf[4][4];
    float idn[4], riq[2][4];

    // ---- prologue: ids(0)->A, frags(0), ids(1)->B ----
    load_ids(qb + (size_t)b0 * QLEN, db + (size_t)b0 * DLEN, w, l15, qidA0, qidA1, didA);
    issue_frags(ebf, inorm, qb + (size_t)b0 * QLEN, quad, qidA0, qidA1, didA,
                a0, a1, bbf, idn, riq);
    load_ids(qb + (size_t)(b0 + 1) * QLEN, db + (size_t)(b0 + 1) * DLEN,
             w, l15, qidB0, qidB1, didB);

    #pragma unroll
    for (int i = t; i < 2 * QLEN * 12; i += 256) ((float*)s_tot)[i] = 0.f;
    __syncthreads();

    // ---- 4 pipeline stages, A/B id sets alternated statically ----
    knrm_unit<0>(ebf, inorm, mlp_w, logits, unit0 + 0,
                 qb + (size_t)(b0 + 1) * QLEN,
                 qb + (size_t)(b0 + 2) * QLEN, db + (size_t)(b0 + 2) * DLEN,
                 w, l15, quad, t, a0, a1, bbf, idn, riq,
                 qidB0, qidB1, didB,            // ids(1): consumed
                 qidA0, qidA1, didA,            // ids(2): loaded
                 wtile, s_tot);
    knrm_unit<1>(ebf, inorm, mlp_w, logits, unit0 + 1,
                 qb + (size_t)(b0 + 2) * QLEN,
                 qb + (size_t)(b0 + 3) * QLEN, db + (size_t)(b0 + 3) * DLEN,
                 w, l15, quad, t, a0, a1, bbf, idn, riq,
                 qidA0, qidA1, didA,            // ids(2): consumed
                 qidB0, qidB1, didB,            // ids(3): loaded
                 wtile, s_tot);
    knrm_unit<2>(ebf, inorm, mlp_w, logits, unit0 + 2,
                 qb + (size_t)(b0 + 3) * QLEN,
                 (const int*)nullptr, (const int*)nullptr,
                 w, l15, quad, t, a0, a1, bbf, idn, riq,
                 qidB0, qidB1, didB,            // ids(3): consumed
                 qidA0, qidA1, didA,            // unused
                 wtile, s_tot);
    knrm_unit<3>(ebf, inorm, mlp_w, logits, unit0 + 3,
                 (const int*)nullptr, (const int*)nullptr, (const int*)nullptr,
                 w, l15, quad, t, a0, a1, bbf, idn, riq,
                 qidA0, qidA1, didA,            // unused
                 qidB0, qidB1, didB,            // unused
                 wtile, s_tot);
}

// ---------------------------------------------------------------------------
// fallback helper: fp32 -> bf16 frag + norm of rounded values
__device__ __forceinline__ bf16x8 cvt8(const float* p, float& nacc)
{
    uint4 a = *((const uint4*)p);
    uint4 b = *((const uint4*)(p + 4));
    unsigned u[8] = {a.x, a.y, a.z, a.w, b.x, b.y, b.z, b.w};
    bf16x8 r;
    #pragma unroll
    for (int i = 0; i < 8; ++i) {
        const unsigned q = u[i] + 0x8000u;
        r[i] = (short)(q >> 16);
        union { unsigned uu; float ff; } g; g.uu = q & 0xFFFF0000u;
        nacc = fmaf(g.ff, g.ff, nacc);
    }
    return r;
}

// legacy pooling (fallback path)
__device__ __forceinline__ void pool_half(float* __restrict__ wtile,
                                          const f32x4* __restrict__ a,
                                          const float* __restrict__ riq,
                                          const float* __restrict__ idn,
                                          float (*__restrict__ stot)[12],
                                          int mtbase, int l15, int quad)
{
    #pragma unroll
    for (int nt = 0; nt < 4; ++nt)
        #pragma unroll
        for (int r = 0; r < 4; ++r)
            wtile[(quad * 4 + r) * SSTR + nt * 16 + l15] = a[nt][r] * riq[r] * idn[nt];

    const float* rp = wtile + l15 * SSTR + quad * 16;
    float ksum[KNUM];
    #pragma unroll
    for (int k = 0; k < KNUM; ++k) ksum[k] = 0.f;
    #pragma unroll
    for (int i = 0; i < 4; ++i)
        chain4(*(const f32x4*)(rp + 4 * i), ksum);
    #pragma unroll
    for (int k = 0; k < KNUM; ++k) {
        ksum[k] += __shfl_xor(ksum[k], 16);
        ksum[k] += __shfl_xor(ksum[k], 32);
    }
    if (quad == 0) {
        #pragma unroll
        for (int k = 0; k < KNUM; ++k)
            atomicAdd(&stot[mtbase + l15][k], ksum[k]);
    }
}

// Legacy kernel, kept as the small-workspace fallback (instantiated <false>).
template<bool PRE>
__global__ __launch_bounds__(256, 4)
void knrm_pair(const float* __restrict__ emb,
               const ushort* __restrict__ ebf,
               const float* __restrict__ inorm,
               const float* __restrict__ mlp_w,
               const int* __restrict__ q1, const int* __restrict__ d1,
               const int* __restrict__ q2, const int* __restrict__ d2,
               float* __restrict__ logits)
{
    const int b    = blockIdx.x;
    const int pair = blockIdx.y;
    const int t    = threadIdx.x;
    const int w    = t >> 6;
    const int l15  = t & 15;
    const int quad = (t & 63) >> 4;

    const int* __restrict__ qry = (pair == 0 ? q1 : q2) + b * QLEN;
    const int* __restrict__ doc = (pair == 0 ? d1 : d2) + b * DLEN;

    __shared__ __align__(16) float s_sim[4 * SHALF];
    __shared__ float s_tot[QLEN][12];

    #pragma unroll
    for (int i = t; i < QLEN * 12; i += 256) ((float*)s_tot)[i] = 0.f;
    __syncthreads();

    const int qid0 = qry[l15], qid1 = qry[l15 + 16];
    int did[4];
    #pragma unroll
    for (int nt = 0; nt < 4; ++nt) did[nt] = doc[(w * 4 + nt) * 16 + l15];

    f32x4 acc[2][4];
    #pragma unroll
    for (int mt = 0; mt < 2; ++mt)
        #pragma unroll
        for (int nt = 0; nt < 4; ++nt)
            acc[mt][nt] = (f32x4){0.f, 0.f, 0.f, 0.f};

    float idn[4], riq[2][4];
    float* wtile = s_sim + w * SHALF;

    {
        float qn2[2] = {0.f, 0.f}, dn2[4] = {0.f, 0.f, 0.f, 0.f};
        const float* qp0 = (const float*)nullptr;
        (void)qp0;
        const float* emb_qp0 = emb + (size_t)qid0 * EMBED + quad * 8;
        const float* emb_qp1 = emb + (size_t)qid1 * EMBED + quad * 8;
        #pragma unroll
        for (int kk = 0; kk < 4; ++kk) {
            const bf16x8 a0 = cvt8(emb_qp0 + kk * 32, qn2[0]);
            const bf16x8 a1 = cvt8(emb_qp1 + kk * 32, qn2[1]);
            #pragma unroll
            for (int nt = 0; nt < 4; ++nt) {
                const bf16x8 bb = cvt8(emb + (size_t)did[nt] * EMBED + quad * 8 + kk * 32, dn2[nt]);
                acc[0][nt] = __builtin_amdgcn_mfma_f32_16x16x32_bf16(a0, bb, acc[0][nt], 0, 0, 0);
                acc[1][nt] = __builtin_amdgcn_mfma_f32_16x16x32_bf16(a1, bb, acc[1][nt], 0, 0, 0);
            }
        }
        #pragma unroll
        for (int i = 0; i < 2; ++i) {
            qn2[i] += __shfl_xor(qn2[i], 16);
            qn2[i] += __shfl_xor(qn2[i], 32);
        }
        #pragma unroll
        for (int nt = 0; nt < 4; ++nt) {
            dn2[nt] += __shfl_xor(dn2[nt], 16);
            dn2[nt] += __shfl_xor(dn2[nt], 32);
            idn[nt] = __builtin_amdgcn_rsqf(dn2[nt]);
        }
        #pragma unroll
        for (int r = 0; r < 4; ++r) {
            riq[0][r] = __builtin_amdgcn_rsqf(__shfl(qn2[0], quad * 4 + r));
            riq[1][r] = __builtin_amdgcn_rsqf(__shfl(qn2[1], quad * 4 + r));
        }
    }

    pool_half(wtile, acc[0], riq[0], idn, s_tot, 0,  l15, quad);
    pool_half(wtile, acc[1], riq[1], idn, s_tot, 16, l15, quad);
    __syncthreads();

    if (t < QLEN) {
        float c = 0.f;
        #pragma unroll
        for (int k = 0; k < KNUM; ++k) c += mlp_w[k] * log1pf(s_tot[t][k]);
        #pragma unroll
        for (int mm = 1; mm < 32; mm <<= 1) c += __shfl_xor(c, mm);
        if (t == 0) logits[pair * NB + b] = c;
    }
}

__global__ __launch_bounds__(256)
void knrm_combine(const float* __restrict__ logits, float* __restrict__ out)
{
    const int i = blockIdx.x * blockDim.x + threadIdx.x;
    if (i < NB) {
        const float d = logits[i] - logits[NB + i];
        out[i] = 1.f / (1.f + __expf(-d));
    }
}

extern "C" void kernel_launch(void* const* d_in, const int* in_sizes, int n_in,
                              void* d_out, int out_size, void* d_ws, size_t ws_size,
                              hipStream_t stream)
{
    const float* emb   = (const float*)d_in[0];
    const float* mlp_w = (const float*)d_in[1];
    // mlp_b (d_in[2]) unused: cancels in logits1 - logits2
    const int* q1 = (const int*)d_in[3];
    const int* d1 = (const int*)d_in[4];
    const int* q2 = (const int*)d_in[5];
    const int* d2 = (const int*)d_in[6];

    float* out = (float*)d_out;

    const size_t need = 2 * NB * 4                       // logits
                      + (size_t)VOCAB * 4                // inorm
                      + (size_t)VOCAB * EMBED * 2 + 256; // bf16 table
    if (ws_size >= need) {
        float*  logits = (float*)d_ws;
        float*  inorm  = logits + 2 * NB;
        ushort* ebf    = (ushort*)(inorm + VOCAB);
        cvt_table<<<VOCAB / 8, 256, 0, stream>>>(emb, ebf, inorm);
        knrm_pair5<<<dim3(2 * NB / 4), 256, 0, stream>>>(ebf, inorm, mlp_w,
                                                         q1, d1, q2, d2, logits);
    } else {
        float* logits = (float*)d_ws;
        knrm_pair<false><<<dim3(NB, 2), 256, 0, stream>>>(emb, nullptr, nullptr, mlp_w,
                                                          q1, d1, q2, d2, logits);
    }
    knrm_combine<<<(NB + 255) / 256, 256, 0, stream>>>((float*)d_ws, out);
}

// Round 6
// 155.866 us; speedup vs baseline: 1.3167x; 1.3167x over previous
//
#include <hip/hip_runtime.h>
#include <math.h>
#include <stdint.h>

#define VOCAB 100000
#define NB    1024
#define QLEN  32
#define DLEN  256
#define EMBED 128
#define KNUM  11

typedef __attribute__((ext_vector_type(8))) short bf16x8;   // 8 bf16 = 4 VGPRs
typedef __attribute__((ext_vector_type(4))) float f32x4;

// Gaussian chain: mus -0.9..0.9 step 0.2 (sigma 0.1) + exact mu=1 sigma=.001
#define HALF_L2E 0.7213475204444817f   // 0.5*log2(e)
#define TWO_L2E  2.8853900817779268f   // 2*log2(e)
#define EM4      0.018315638888734179f // e^-4

#define SSTR  68                 // sim row stride (floats)
#define SHALF (16 * SSTR)

// ---------- prepass: fp32 table -> bf16 table + bf16-consistent inv-norms ----
__global__ __launch_bounds__(256)
void cvt_table(const float* __restrict__ emb, ushort* __restrict__ ebf,
               float* __restrict__ inorm)
{
    const int row = blockIdx.x * 8 + (threadIdx.x >> 5);
    const int l32 = threadIdx.x & 31;
    const float4 v = *((const float4*)(emb + (size_t)row * EMBED) + l32);
    union { float f; unsigned u; } x0, x1, x2, x3;
    x0.f = v.x; x1.f = v.y; x2.f = v.z; x3.f = v.w;
    const unsigned r0 = x0.u + 0x8000u, r1 = x1.u + 0x8000u;  // round-half-up
    const unsigned r2 = x2.u + 0x8000u, r3 = x3.u + 0x8000u;
    uint2 packed;
    packed.x = (r0 >> 16) | (r1 & 0xFFFF0000u);
    packed.y = (r2 >> 16) | (r3 & 0xFFFF0000u);
    *((uint2*)(ebf + (size_t)row * EMBED) + l32) = packed;
    x0.u = r0 & 0xFFFF0000u; x1.u = r1 & 0xFFFF0000u;
    x2.u = r2 & 0xFFFF0000u; x3.u = r3 & 0xFFFF0000u;
    float n = x0.f * x0.f + x1.f * x1.f + x2.f * x2.f + x3.f * x3.f;
    #pragma unroll
    for (int m = 1; m < 32; m <<= 1) n += __shfl_xor(n, m);
    if (l32 == 0) inorm[row] = __builtin_amdgcn_rsqf(n);
}

// the 11-kernel exp chain on 4 sims (byte-identical to the proven kernel)
__device__ __forceinline__ void chain4(const f32x4 sv, float (&ksum)[KNUM])
{
    #pragma unroll
    for (int e = 0; e < 4; ++e) {
        const float s  = sv[e];
        const float z  = fmaf(s, 10.f, -1.f);
        const float e0 = exp2f(-HALF_L2E * (z * z));
        float ru = exp2f(fmaf(z,  TWO_L2E, -TWO_L2E));
        float rd = exp2f(fmaf(z, -TWO_L2E, -TWO_L2E));
        ksum[5] += e0;
        float tt = e0;
        tt *= ru; ksum[6] += tt; ru *= EM4;
        tt *= ru; ksum[7] += tt; ru *= EM4;
        tt *= ru; ksum[8] += tt; ru *= EM4;
        tt *= ru; ksum[9] += tt;
        tt = e0;
        tt *= rd; ksum[4] += tt; rd *= EM4;
        tt *= rd; ksum[3] += tt; rd *= EM4;
        tt *= rd; ksum[2] += tt; rd *= EM4;
        tt *= rd; ksum[1] += tt; rd *= EM4;
        tt *= rd; ksum[0] += tt;
        // exact kernel (sigma=.001): ==1 iff token match (bf16 self-sim
        // 1+-3e-6; non-match needs cos>0.995 ~ 11 sigma)
        ksum[10] += (s > 0.995f) ? 1.f : 0.f;
    }
}

// pool one 16-row half-tile (proven r4 code, unchanged)
__device__ __forceinline__ void pool_half(float* __restrict__ wtile,
                                          const f32x4* __restrict__ a,   // [4] nt
                                          const float* __restrict__ riq, // [4] r
                                          const float* __restrict__ idn, // [4] nt
                                          float (*__restrict__ stot)[12],
                                          int mtbase, int l15, int quad)
{
    #pragma unroll
    for (int nt = 0; nt < 4; ++nt)
        #pragma unroll
        for (int r = 0; r < 4; ++r)
            wtile[(quad * 4 + r) * SSTR + nt * 16 + l15] = a[nt][r] * riq[r] * idn[nt];

    const float* rp = wtile + l15 * SSTR + quad * 16;   // row l15, chunk quad
    float ksum[KNUM];
    #pragma unroll
    for (int k = 0; k < KNUM; ++k) ksum[k] = 0.f;
    #pragma unroll
    for (int i = 0; i < 4; ++i)
        chain4(*(const f32x4*)(rp + 4 * i), ksum);
    #pragma unroll
    for (int k = 0; k < KNUM; ++k) {
        ksum[k] += __shfl_xor(ksum[k], 16);
        ksum[k] += __shfl_xor(ksum[k], 32);
    }
    if (quad == 0) {
        #pragma unroll
        for (int k = 0; k < KNUM; ++k)
            atomicAdd(&stot[mtbase + l15][k], ksum[k]);
    }
}

// ---------------------------------------------------------------------------
// Round-6: COALESCED gathers + LDS transpose. The r0-r4 structure's wall is
// address-transaction throughput: per-lane-distinct-row gathers cost 64 cache
// lines per wave-instruction (~98k lines/CU ~= 41us at ~1 line/cy — the
// observed 50us floor). Here 16 consecutive lanes read one row's 256B
// (4 rows/instr, ~8 lines/instr); fragments are re-ordered through LDS with
// the additive swizzle pos(r,s) = s*16 + ((r+s)&15)  [16B units], which makes
// BOTH the staging ds_write_b128 and the fragment ds_read_b128 uniform
// 8-lanes-per-bank-quad (minimum wave64 aliasing = free). Doc norms staged
// once (coalesced-gather -> LDS broadcast). MFMA mapping, pool, reduction
// byte-identical to the 49.7us kernel.
// LDS: doc 64KB + q 8KB + norms 1.2KB + s_tot 1.5KB = 74.6KB -> 2 blocks/CU.
// Sim tiles OVERLAY the (dead after MFMA) wave-private doc region.
__global__ __launch_bounds__(256, 2)
void knrm_pair6(const ushort* __restrict__ ebf,
                const float* __restrict__ inorm,
                const float* __restrict__ mlp_w,
                const int* __restrict__ q1, const int* __restrict__ d1,
                const int* __restrict__ q2, const int* __restrict__ d2,
                float* __restrict__ logits)
{
    const int b    = blockIdx.x;
    const int pair = blockIdx.y;
    const int t    = threadIdx.x;
    const int w    = t >> 6;        // wave id: doc tiles w*4..w*4+3
    const int l    = t & 63;
    const int l15  = l & 15;
    const int quad = l >> 4;

    const int* __restrict__ qry = (pair == 0 ? q1 : q2) + b * QLEN;
    const int* __restrict__ doc = (pair == 0 ? d1 : d2) + b * DLEN;

    // frag store: doc tiles 0..15 (16-row tiles, 256 x 16B each), then q tiles
    __shared__ __align__(16) uint4 s_frag[16 * 256 + 2 * 256];  // 73728 B
    __shared__ float s_dnorm[DLEN];                             // 1024 B
    __shared__ float s_qnorm[QLEN];                             // 128 B
    __shared__ float s_tot[QLEN][12];                           // 1536 B

    // swizzled position of (row r, 16B-slot s) within a 16-row tile
    #define TPOS(r, s) ((s) * 16 + (((r) + (s)) & 15))

    // ---- staging: coalesced 256B-row loads, swizzled ds_write ----
    // doc: wave w stages its own 64 rows (tiles w*4..w*4+3), 4 rows/instr
    #pragma unroll
    for (int j = 0; j < 4; ++j)
        #pragma unroll
        for (int i = 0; i < 4; ++i) {
            const int r  = 4 * i + quad;                    // row within tile
            const int id = doc[w * 64 + j * 16 + r];        // 4 addrs, 1 line
            const uint4 v = *(const uint4*)(ebf + (size_t)id * EMBED + l15 * 8);
            s_frag[(w * 4 + j) * 256 + TPOS(r, l15)] = v;
        }
    // q: wave w stages rows w*8..w*8+7 (tile mt=w>>1, local (w&1)*8..+7)
    {
        const int mt = w >> 1;
        #pragma unroll
        for (int i = 0; i < 2; ++i) {
            const int r  = (w & 1) * 8 + 4 * i + quad;
            const int id = qry[mt * 16 + r];
            const uint4 v = *(const uint4*)(ebf + (size_t)id * EMBED + l15 * 8);
            s_frag[4096 + mt * 256 + TPOS(r, l15)] = v;
        }
    }
    // norms: one coalesced-gather pass each, broadcast later from LDS
    s_dnorm[w * 64 + l] = inorm[doc[w * 64 + l]];
    if (t < QLEN) s_qnorm[t] = inorm[qry[t]];
    #pragma unroll
    for (int i = t; i < QLEN * 12; i += 256) ((float*)s_tot)[i] = 0.f;

    __syncthreads();    // all staged frags + norms visible (q shared)

    // ---- MFMA: fragments from LDS (lane l15 = row, slot quad+4kk) ----
    f32x4 acc[2][4];
    #pragma unroll
    for (int mt = 0; mt < 2; ++mt)
        #pragma unroll
        for (int j = 0; j < 4; ++j)
            acc[mt][j] = (f32x4){0.f, 0.f, 0.f, 0.f};
    #pragma unroll
    for (int kk = 0; kk < 4; ++kk) {
        const int s = quad + 4 * kk;
        const bf16x8 a0 = *(const bf16x8*)&s_frag[4096 +       TPOS(l15, s)];
        const bf16x8 a1 = *(const bf16x8*)&s_frag[4096 + 256 + TPOS(l15, s)];
        #pragma unroll
        for (int j = 0; j < 4; ++j) {
            const bf16x8 bb = *(const bf16x8*)&s_frag[(w * 4 + j) * 256 + TPOS(l15, s)];
            acc[0][j] = __builtin_amdgcn_mfma_f32_16x16x32_bf16(a0, bb, acc[0][j], 0, 0, 0);
            acc[1][j] = __builtin_amdgcn_mfma_f32_16x16x32_bf16(a1, bb, acc[1][j], 0, 0, 0);
        }
    }

    // norms from LDS (broadcast reads, free)
    float idn[4];
    #pragma unroll
    for (int j = 0; j < 4; ++j) idn[j] = s_dnorm[w * 64 + j * 16 + l15];
    float riq[2][4];
    #pragma unroll
    for (int r = 0; r < 4; ++r) {
        riq[0][r] = s_qnorm[quad * 4 + r];
        riq[1][r] = s_qnorm[16 + quad * 4 + r];
    }

    // overlay safety: all frag/norm ds_reads must retire before sim ds_writes
    // reuse their LDS (rule #18: lgkmcnt fence + sched_barrier)
    asm volatile("s_waitcnt lgkmcnt(0)" ::: "memory");
    __builtin_amdgcn_sched_barrier(0);

    // ---- pooling on the (dead) wave-private doc region ----
    float* wtile = (float*)s_frag + w * 4096;   // w*16KB, needs 4.3KB
    pool_half(wtile, acc[0], riq[0], idn, s_tot, 0,  l15, quad);
    pool_half(wtile, acc[1], riq[1], idn, s_tot, 16, l15, quad);
    __syncthreads();

    if (t < QLEN) {
        float c = 0.f;
        #pragma unroll
        for (int k = 0; k < KNUM; ++k) c += mlp_w[k] * log1pf(s_tot[t][k]);
        #pragma unroll
        for (int mm = 1; mm < 32; mm <<= 1) c += __shfl_xor(c, mm);
        if (t == 0) logits[pair * NB + b] = c;   // mlp bias cancels in l1-l2
    }
    #undef TPOS
}

// ---------------------------------------------------------------------------
// fallback helper: fp32 -> bf16 frag + norm of rounded values
__device__ __forceinline__ bf16x8 cvt8(const float* p, float& nacc)
{
    uint4 a = *((const uint4*)p);
    uint4 b = *((const uint4*)(p + 4));
    unsigned u[8] = {a.x, a.y, a.z, a.w, b.x, b.y, b.z, b.w};
    bf16x8 r;
    #pragma unroll
    for (int i = 0; i < 8; ++i) {
        const unsigned q = u[i] + 0x8000u;
        r[i] = (short)(q >> 16);
        union { unsigned uu; float ff; } g; g.uu = q & 0xFFFF0000u;
        nacc = fmaf(g.ff, g.ff, nacc);
    }
    return r;
}

// Legacy kernel, kept as the small-workspace fallback.
__global__ __launch_bounds__(256, 4)
void knrm_pair_fb(const float* __restrict__ emb,
                  const float* __restrict__ mlp_w,
                  const int* __restrict__ q1, const int* __restrict__ d1,
                  const int* __restrict__ q2, const int* __restrict__ d2,
                  float* __restrict__ logits)
{
    const int b    = blockIdx.x;
    const int pair = blockIdx.y;
    const int t    = threadIdx.x;
    const int w    = t >> 6;
    const int l15  = t & 15;
    const int quad = (t & 63) >> 4;

    const int* __restrict__ qry = (pair == 0 ? q1 : q2) + b * QLEN;
    const int* __restrict__ doc = (pair == 0 ? d1 : d2) + b * DLEN;

    __shared__ __align__(16) float s_sim[4 * SHALF];
    __shared__ float s_tot[QLEN][12];

    #pragma unroll
    for (int i = t; i < QLEN * 12; i += 256) ((float*)s_tot)[i] = 0.f;
    __syncthreads();

    const int qid0 = qry[l15], qid1 = qry[l15 + 16];
    int did[4];
    #pragma unroll
    for (int nt = 0; nt < 4; ++nt) did[nt] = doc[(w * 4 + nt) * 16 + l15];

    f32x4 acc[2][4];
    #pragma unroll
    for (int mt = 0; mt < 2; ++mt)
        #pragma unroll
        for (int nt = 0; nt < 4; ++nt)
            acc[mt][nt] = (f32x4){0.f, 0.f, 0.f, 0.f};

    float idn[4], riq[2][4];
    float* wtile = s_sim + w * SHALF;

    {
        float qn2[2] = {0.f, 0.f}, dn2[4] = {0.f, 0.f, 0.f, 0.f};
        const float* qp0 = emb + (size_t)qid0 * EMBED + quad * 8;
        const float* qp1 = emb + (size_t)qid1 * EMBED + quad * 8;
        #pragma unroll
        for (int kk = 0; kk < 4; ++kk) {
            const bf16x8 a0 = cvt8(qp0 + kk * 32, qn2[0]);
            const bf16x8 a1 = cvt8(qp1 + kk * 32, qn2[1]);
            #pragma unroll
            for (int nt = 0; nt < 4; ++nt) {
                const bf16x8 bb = cvt8(emb + (size_t)did[nt] * EMBED + quad * 8 + kk * 32, dn2[nt]);
                acc[0][nt] = __builtin_amdgcn_mfma_f32_16x16x32_bf16(a0, bb, acc[0][nt], 0, 0, 0);
                acc[1][nt] = __builtin_amdgcn_mfma_f32_16x16x32_bf16(a1, bb, acc[1][nt], 0, 0, 0);
            }
        }
        #pragma unroll
        for (int i = 0; i < 2; ++i) {
            qn2[i] += __shfl_xor(qn2[i], 16);
            qn2[i] += __shfl_xor(qn2[i], 32);
        }
        #pragma unroll
        for (int nt = 0; nt < 4; ++nt) {
            dn2[nt] += __shfl_xor(dn2[nt], 16);
            dn2[nt] += __shfl_xor(dn2[nt], 32);
            idn[nt] = __builtin_amdgcn_rsqf(dn2[nt]);
        }
        #pragma unroll
        for (int r = 0; r < 4; ++r) {
            riq[0][r] = __builtin_amdgcn_rsqf(__shfl(qn2[0], quad * 4 + r));
            riq[1][r] = __builtin_amdgcn_rsqf(__shfl(qn2[1], quad * 4 + r));
        }
    }

    pool_half(wtile, acc[0], riq[0], idn, s_tot, 0,  l15, quad);
    pool_half(wtile, acc[1], riq[1], idn, s_tot, 16, l15, quad);
    __syncthreads();

    if (t < QLEN) {
        float c = 0.f;
        #pragma unroll
        for (int k = 0; k < KNUM; ++k) c += mlp_w[k] * log1pf(s_tot[t][k]);
        #pragma unroll
        for (int mm = 1; mm < 32; mm <<= 1) c += __shfl_xor(c, mm);
        if (t == 0) logits[pair * NB + b] = c;
    }
}

__global__ __launch_bounds__(256)
void knrm_combine(const float* __restrict__ logits, float* __restrict__ out)
{
    const int i = blockIdx.x * blockDim.x + threadIdx.x;
    if (i < NB) {
        const float d = logits[i] - logits[NB + i];
        out[i] = 1.f / (1.f + __expf(-d));
    }
}

extern "C" void kernel_launch(void* const* d_in, const int* in_sizes, int n_in,
                              void* d_out, int out_size, void* d_ws, size_t ws_size,
                              hipStream_t stream)
{
    const float* emb   = (const float*)d_in[0];
    const float* mlp_w = (const float*)d_in[1];
    // mlp_b (d_in[2]) unused: cancels in logits1 - logits2
    const int* q1 = (const int*)d_in[3];
    const int* d1 = (const int*)d_in[4];
    const int* q2 = (const int*)d_in[5];
    const int* d2 = (const int*)d_in[6];

    float* out = (float*)d_out;

    const size_t need = 2 * NB * 4                       // logits
                      + (size_t)VOCAB * 4                // inorm
                      + (size_t)VOCAB * EMBED * 2 + 256; // bf16 table
    if (ws_size >= need) {
        float*  logits = (float*)d_ws;
        float*  inorm  = logits + 2 * NB;
        ushort* ebf    = (ushort*)(inorm + VOCAB);
        cvt_table<<<VOCAB / 8, 256, 0, stream>>>(emb, ebf, inorm);
        knrm_pair6<<<dim3(NB, 2), 256, 0, stream>>>(ebf, inorm, mlp_w,
                                                    q1, d1, q2, d2, logits);
    } else {
        float* logits = (float*)d_ws;
        knrm_pair_fb<<<dim3(NB, 2), 256, 0, stream>>>(emb, mlp_w,
                                                      q1, d1, q2, d2, logits);
    }
    knrm_combine<<<(NB + 255) / 256, 256, 0, stream>>>((float*)d_ws, out);
}

// Round 8
// 147.126 us; speedup vs baseline: 1.3950x; 1.0594x over previous
//
#include <hip/hip_runtime.h>
#include <math.h>
#include <stdint.h>

#define VOCAB 100000
#define NB    1024
#define QLEN  32
#define DLEN  256
#define EMBED 128
#define KNUM  11

typedef __attribute__((ext_vector_type(8))) short bf16x8;   // 8 bf16 = 4 VGPRs
typedef __attribute__((ext_vector_type(4))) float f32x4;

// Gaussian chain: mus -0.9..0.9 step 0.2 (sigma 0.1) + exact mu=1 sigma=.001
#define HALF_L2E 0.7213475204444817f   // 0.5*log2(e)
#define TWO_L2E  2.8853900817779268f   // 2*log2(e)
#define EM4      0.018315638888734179f // e^-4

#define SSTR  68                 // sim row stride (floats): 2-lane/bank = free
#define SHALF (16 * SSTR)        // 1088 floats = 4352 B (per-wave region)

// ---------- prepass: fp32 table -> bf16 table (no norm pass needed now) ----
__global__ __launch_bounds__(256)
void cvt_table(const float* __restrict__ emb, ushort* __restrict__ ebf)
{
    const int row = blockIdx.x * 8 + (threadIdx.x >> 5);
    const int l32 = threadIdx.x & 31;
    const float4 v = *((const float4*)(emb + (size_t)row * EMBED) + l32);
    union { float f; unsigned u; } x0, x1, x2, x3;
    x0.f = v.x; x1.f = v.y; x2.f = v.z; x3.f = v.w;
    const unsigned r0 = x0.u + 0x8000u, r1 = x1.u + 0x8000u;  // round-half-up
    const unsigned r2 = x2.u + 0x8000u, r3 = x3.u + 0x8000u;
    uint2 packed;
    packed.x = (r0 >> 16) | (r1 & 0xFFFF0000u);
    packed.y = (r2 >> 16) | (r3 & 0xFFFF0000u);
    *((uint2*)(ebf + (size_t)row * EMBED) + l32) = packed;
}

// the 11-kernel exp chain on 4 sims (byte-identical to the proven kernel)
__device__ __forceinline__ void chain4(const f32x4 sv, float (&ksum)[KNUM])
{
    #pragma unroll
    for (int e = 0; e < 4; ++e) {
        const float s  = sv[e];
        const float z  = fmaf(s, 10.f, -1.f);
        const float e0 = exp2f(-HALF_L2E * (z * z));
        float ru = exp2f(fmaf(z,  TWO_L2E, -TWO_L2E));
        float rd = exp2f(fmaf(z, -TWO_L2E, -TWO_L2E));
        ksum[5] += e0;
        float tt = e0;
        tt *= ru; ksum[6] += tt; ru *= EM4;
        tt *= ru; ksum[7] += tt; ru *= EM4;
        tt *= ru; ksum[8] += tt; ru *= EM4;
        tt *= ru; ksum[9] += tt;
        tt = e0;
        tt *= rd; ksum[4] += tt; rd *= EM4;
        tt *= rd; ksum[3] += tt; rd *= EM4;
        tt *= rd; ksum[2] += tt; rd *= EM4;
        tt *= rd; ksum[1] += tt; rd *= EM4;
        tt *= rd; ksum[0] += tt;
        // exact kernel (sigma=.001): ==1 iff token match (bf16 self-sim
        // 1+-3e-6; non-match needs cos>0.995 ~ 11 sigma)
        ksum[10] += (s > 0.995f) ? 1.f : 0.f;
    }
}

// pool one 16-row half-tile (proven legacy code, unchanged)
__device__ __forceinline__ void pool_half(float* __restrict__ wtile,
                                          const f32x4* __restrict__ a,   // [4] nt
                                          const float* __restrict__ riq, // [4] r
                                          const float* __restrict__ idn, // [4] nt
                                          float (*__restrict__ stot)[12],
                                          int mtbase, int l15, int quad)
{
    #pragma unroll
    for (int nt = 0; nt < 4; ++nt)
        #pragma unroll
        for (int r = 0; r < 4; ++r)
            wtile[(quad * 4 + r) * SSTR + nt * 16 + l15] = a[nt][r] * riq[r] * idn[nt];

    const float* rp = wtile + l15 * SSTR + quad * 16;
    float ksum[KNUM];
    #pragma unroll
    for (int k = 0; k < KNUM; ++k) ksum[k] = 0.f;
    #pragma unroll
    for (int i = 0; i < 4; ++i)
        chain4(*(const f32x4*)(rp + 4 * i), ksum);
    #pragma unroll
    for (int k = 0; k < KNUM; ++k) {
        ksum[k] += __shfl_xor(ksum[k], 16);
        ksum[k] += __shfl_xor(ksum[k], 32);
    }
    if (quad == 0) {
        #pragma unroll
        for (int k = 0; k < KNUM; ++k)
            atomicAdd(&stot[mtbase + l15][k], ksum[k]);
    }
}

// sumsq of 8 bf16 lanes-local elements (bit-exact bf16->f32 via <<16)
__device__ __forceinline__ float sumsq8(const bf16x8 v, float acc)
{
    #pragma unroll
    for (int e = 0; e < 8; ++e) {
        union { unsigned u; float f; } g;
        g.u = ((unsigned)(unsigned short)v[e]) << 16;
        acc = fmaf(g.f, g.f, acc);
    }
    return acc;
}

// ---------------------------------------------------------------------------
// Round-7 (resubmitted unchanged after infra failure): r4's proven shape
// (4 waves, wave-private tiles, legacy pooling, no hot-path barriers) +
// coalesced row loads. Wave w streams its 4 doc tiles through ITS OWN
// 4.35KB LDS region (later reused for sims): coalesced 16B/lane loads
// (16 lines/instr vs 64 scattered), 1-tile register prefetch (T14 split),
// XOR unit-swizzle pos(r,s)=r*16+((s^r)&15) — conflict-minimal on BOTH
// ds_write (r varies per lane) and ds_read_b128 (s varies per lane).
// q rows staged once to shared LDS (1 barrier, outside the loop). All norms
// computed in-register from the staged bf16 frags (no scattered norm gathers,
// no inorm table at all). Line-txns/block: ~9.5k -> ~1.3k (7x).
// MFMA mapping + pooling byte-identical to the 49.7us kernel.
__global__ __launch_bounds__(256, 4)
void knrm_pair7(const ushort* __restrict__ ebf,
                const float* __restrict__ mlp_w,
                const int* __restrict__ q1, const int* __restrict__ d1,
                const int* __restrict__ q2, const int* __restrict__ d2,
                float* __restrict__ logits)
{
    const int b    = blockIdx.x;
    const int pair = blockIdx.y;
    const int t    = threadIdx.x;
    const int w    = t >> 6;        // wave id: doc tiles w*4..w*4+3
    const int l    = t & 63;
    const int l15  = l & 15;
    const int quad = l >> 4;

    const int* __restrict__ qry = (pair == 0 ? q1 : q2) + b * QLEN;
    const int* __restrict__ doc = (pair == 0 ? d1 : d2) + b * DLEN;

    // per-wave region: doc-tile staging (256 uint4 = 4KB) OR sim half-tile
    // (16 x SSTR floats = 4352B). s_q: 2 q tiles, swizzled, shared.
    __shared__ __align__(16) float s_buf[4][SHALF];     // 17408 B
    __shared__ __align__(16) uint4 s_q[2 * 256];        // 8192 B
    __shared__ float s_tot[QLEN][12];                   // 1536 B

    // swizzled 16B-unit index inside a 16-row tile: row r, slot s (both 0-15)
    #define SWZ(r, s) (((r) << 4) | (((s) ^ (r)) & 15))

    uint4* wbuf = (uint4*)&s_buf[w][0];

    // ---- stage q rows (coalesced, 2 instr/wave): wave w -> rows w*8..w*8+7 ----
    #pragma unroll
    for (int i = 0; i < 2; ++i) {
        const int row = w * 8 + i * 4 + quad;           // q row 0..31
        const int id  = qry[row];                        // 8 distinct ints, 1 line
        const uint4 v = *(const uint4*)(ebf + (size_t)id * EMBED + l15 * 8);
        s_q[(row >> 4) * 256 + SWZ(row & 15, l15)] = v;
    }
    #pragma unroll
    for (int i = t; i < QLEN * 12; i += 256) ((float*)s_tot)[i] = 0.f;
    __syncthreads();                                     // q tiles + s_tot ready

    // ---- A-frags + q norms from LDS (frag = row l15, cols (quad+4kk)*8..+8) ----
    bf16x8 a0[4], a1[4];
    float qn0 = 0.f, qn1 = 0.f;
    #pragma unroll
    for (int kk = 0; kk < 4; ++kk) {
        const int s = quad + 4 * kk;
        a0[kk] = *(const bf16x8*)&s_q[      SWZ(l15, s)];
        a1[kk] = *(const bf16x8*)&s_q[256 + SWZ(l15, s)];
        qn0 = sumsq8(a0[kk], qn0);
        qn1 = sumsq8(a1[kk], qn1);
    }
    qn0 += __shfl_xor(qn0, 16); qn0 += __shfl_xor(qn0, 32);  // reduce quads
    qn1 += __shfl_xor(qn1, 16); qn1 += __shfl_xor(qn1, 32);
    float riq[2][4];
    #pragma unroll
    for (int r = 0; r < 4; ++r) {                        // lane quad*4+r holds row quad*4+r
        riq[0][r] = __builtin_amdgcn_rsqf(__shfl(qn0, quad * 4 + r));
        riq[1][r] = __builtin_amdgcn_rsqf(__shfl(qn1, quad * 4 + r));
    }

    // ---- doc tiles: stream through wbuf with 1-tile register prefetch ----
    f32x4 acc[2][4];
    #pragma unroll
    for (int mt = 0; mt < 2; ++mt)
        #pragma unroll
        for (int j = 0; j < 4; ++j)
            acc[mt][j] = (f32x4){0.f, 0.f, 0.f, 0.f};
    float idn[4];
    uint4 pf[4];

    // prefetch tile 0: 4 coalesced row-loads (ids: 16 ints within 1 line each)
    #pragma unroll
    for (int i = 0; i < 4; ++i) {
        const int id = doc[w * 64 + 4 * i + quad];
        pf[i] = *(const uint4*)(ebf + (size_t)id * EMBED + l15 * 8);
    }

    #pragma unroll
    for (int j = 0; j < 4; ++j) {
        // commit staged tile j (vmcnt wait auto via pf data dep)
        #pragma unroll
        for (int i = 0; i < 4; ++i)
            wbuf[SWZ(4 * i + quad, l15)] = pf[i];
        // issue next tile's loads (consumed next iter -> latency hides under MFMA)
        if (j < 3) {
            #pragma unroll
            for (int i = 0; i < 4; ++i) {
                const int id = doc[w * 64 + (j + 1) * 16 + 4 * i + quad];
                pf[i] = *(const uint4*)(ebf + (size_t)id * EMBED + l15 * 8);
            }
        }
        // writes visible before reads; nothing crosses (rule #18)
        asm volatile("s_waitcnt lgkmcnt(0)" ::: "memory");
        __builtin_amdgcn_sched_barrier(0);

        // B-frags + doc norm for tile j (frag rows = l15, same mapping as legacy)
        bf16x8 bb[4];
        float dn = 0.f;
        #pragma unroll
        for (int kk = 0; kk < 4; ++kk) {
            bb[kk] = *(const bf16x8*)&wbuf[SWZ(l15, quad + 4 * kk)];
            dn = sumsq8(bb[kk], dn);
        }
        dn += __shfl_xor(dn, 16); dn += __shfl_xor(dn, 32);
        idn[j] = __builtin_amdgcn_rsqf(dn);

        #pragma unroll
        for (int kk = 0; kk < 4; ++kk) {
            acc[0][j] = __builtin_amdgcn_mfma_f32_16x16x32_bf16(a0[kk], bb[kk], acc[0][j], 0, 0, 0);
            acc[1][j] = __builtin_amdgcn_mfma_f32_16x16x32_bf16(a1[kk], bb[kk], acc[1][j], 0, 0, 0);
        }
        // next iter's ds_writes must stay below this iter's ds_reads
        __builtin_amdgcn_sched_barrier(0);
    }

    // ---- sims overlay wbuf (tile data dead; all reads consumed via data deps) ----
    float* wtile = &s_buf[w][0];
    pool_half(wtile, acc[0], riq[0], idn, s_tot, 0,  l15, quad);
    pool_half(wtile, acc[1], riq[1], idn, s_tot, 16, l15, quad);
    __syncthreads();

    if (t < QLEN) {
        float c = 0.f;
        #pragma unroll
        for (int k = 0; k < KNUM; ++k) c += mlp_w[k] * log1pf(s_tot[t][k]);
        #pragma unroll
        for (int mm = 1; mm < 32; mm <<= 1) c += __shfl_xor(c, mm);
        if (t == 0) logits[pair * NB + b] = c;   // mlp bias cancels in l1-l2
    }
    #undef SWZ
}

// ---------------------------------------------------------------------------
// fallback helper: fp32 -> bf16 frag + norm of rounded values
__device__ __forceinline__ bf16x8 cvt8(const float* p, float& nacc)
{
    uint4 a = *((const uint4*)p);
    uint4 b = *((const uint4*)(p + 4));
    unsigned u[8] = {a.x, a.y, a.z, a.w, b.x, b.y, b.z, b.w};
    bf16x8 r;
    #pragma unroll
    for (int i = 0; i < 8; ++i) {
        const unsigned q = u[i] + 0x8000u;
        r[i] = (short)(q >> 16);
        union { unsigned uu; float ff; } g; g.uu = q & 0xFFFF0000u;
        nacc = fmaf(g.ff, g.ff, nacc);
    }
    return r;
}

// Legacy kernel, kept as the small-workspace fallback (fp32 path).
__global__ __launch_bounds__(256, 4)
void knrm_pair_fb(const float* __restrict__ emb,
                  const float* __restrict__ mlp_w,
                  const int* __restrict__ q1, const int* __restrict__ d1,
                  const int* __restrict__ q2, const int* __restrict__ d2,
                  float* __restrict__ logits)
{
    const int b    = blockIdx.x;
    const int pair = blockIdx.y;
    const int t    = threadIdx.x;
    const int w    = t >> 6;
    const int l15  = t & 15;
    const int quad = (t & 63) >> 4;

    const int* __restrict__ qry = (pair == 0 ? q1 : q2) + b * QLEN;
    const int* __restrict__ doc = (pair == 0 ? d1 : d2) + b * DLEN;

    __shared__ __align__(16) float s_sim[4 * SHALF];
    __shared__ float s_tot[QLEN][12];

    #pragma unroll
    for (int i = t; i < QLEN * 12; i += 256) ((float*)s_tot)[i] = 0.f;
    __syncthreads();

    const int qid0 = qry[l15], qid1 = qry[l15 + 16];
    int did[4];
    #pragma unroll
    for (int nt = 0; nt < 4; ++nt) did[nt] = doc[(w * 4 + nt) * 16 + l15];

    f32x4 acc[2][4];
    #pragma unroll
    for (int mt = 0; mt < 2; ++mt)
        #pragma unroll
        for (int nt = 0; nt < 4; ++nt)
            acc[mt][nt] = (f32x4){0.f, 0.f, 0.f, 0.f};

    float idn[4], riq[2][4];
    float* wtile = s_sim + w * SHALF;

    {
        float qn2[2] = {0.f, 0.f}, dn2[4] = {0.f, 0.f, 0.f, 0.f};
        const float* qp0 = emb + (size_t)qid0 * EMBED + quad * 8;
        const float* qp1 = emb + (size_t)qid1 * EMBED + quad * 8;
        #pragma unroll
        for (int kk = 0; kk < 4; ++kk) {
            const bf16x8 a0 = cvt8(qp0 + kk * 32, qn2[0]);
            const bf16x8 a1 = cvt8(qp1 + kk * 32, qn2[1]);
            #pragma unroll
            for (int nt = 0; nt < 4; ++nt) {
                const bf16x8 bb = cvt8(emb + (size_t)did[nt] * EMBED + quad * 8 + kk * 32, dn2[nt]);
                acc[0][nt] = __builtin_amdgcn_mfma_f32_16x16x32_bf16(a0, bb, acc[0][nt], 0, 0, 0);
                acc[1][nt] = __builtin_amdgcn_mfma_f32_16x16x32_bf16(a1, bb, acc[1][nt], 0, 0, 0);
            }
        }
        #pragma unroll
        for (int i = 0; i < 2; ++i) {
            qn2[i] += __shfl_xor(qn2[i], 16);
            qn2[i] += __shfl_xor(qn2[i], 32);
        }
        #pragma unroll
        for (int nt = 0; nt < 4; ++nt) {
            dn2[nt] += __shfl_xor(dn2[nt], 16);
            dn2[nt] += __shfl_xor(dn2[nt], 32);
            idn[nt] = __builtin_amdgcn_rsqf(dn2[nt]);
        }
        #pragma unroll
        for (int r = 0; r < 4; ++r) {
            riq[0][r] = __builtin_amdgcn_rsqf(__shfl(qn2[0], quad * 4 + r));
            riq[1][r] = __builtin_amdgcn_rsqf(__shfl(qn2[1], quad * 4 + r));
        }
    }

    pool_half(wtile, acc[0], riq[0], idn, s_tot, 0,  l15, quad);
    pool_half(wtile, acc[1], riq[1], idn, s_tot, 16, l15, quad);
    __syncthreads();

    if (t < QLEN) {
        float c = 0.f;
        #pragma unroll
        for (int k = 0; k < KNUM; ++k) c += mlp_w[k] * log1pf(s_tot[t][k]);
        #pragma unroll
        for (int mm = 1; mm < 32; mm <<= 1) c += __shfl_xor(c, mm);
        if (t == 0) logits[pair * NB + b] = c;
    }
}

__global__ __launch_bounds__(256)
void knrm_combine(const float* __restrict__ logits, float* __restrict__ out)
{
    const int i = blockIdx.x * blockDim.x + threadIdx.x;
    if (i < NB) {
        const float d = logits[i] - logits[NB + i];
        out[i] = 1.f / (1.f + __expf(-d));
    }
}

extern "C" void kernel_launch(void* const* d_in, const int* in_sizes, int n_in,
                              void* d_out, int out_size, void* d_ws, size_t ws_size,
                              hipStream_t stream)
{
    const float* emb   = (const float*)d_in[0];
    const float* mlp_w = (const float*)d_in[1];
    // mlp_b (d_in[2]) unused: cancels in logits1 - logits2
    const int* q1 = (const int*)d_in[3];
    const int* d1 = (const int*)d_in[4];
    const int* q2 = (const int*)d_in[5];
    const int* d2 = (const int*)d_in[6];

    float* out = (float*)d_out;

    const size_t need = 2 * NB * 4                       // logits
                      + (size_t)VOCAB * EMBED * 2 + 256; // bf16 table
    if (ws_size >= need) {
        float*  logits = (float*)d_ws;
        ushort* ebf    = (ushort*)(logits + 2 * NB);
        cvt_table<<<VOCAB / 8, 256, 0, stream>>>(emb, ebf);
        knrm_pair7<<<dim3(NB, 2), 256, 0, stream>>>(ebf, mlp_w,
                                                    q1, d1, q2, d2, logits);
    } else {
        float* logits = (float*)d_ws;
        knrm_pair_fb<<<dim3(NB, 2), 256, 0, stream>>>(emb, mlp_w,
                                                      q1, d1, q2, d2, logits);
    }
    knrm_combine<<<(NB + 255) / 256, 256, 0, stream>>>((float*)d_ws, out);
}